// Round 11
// baseline (272.822 us; speedup 1.0000x reference)
//
#include <hip/hip_runtime.h>
#include <hip/hip_bf16.h>

#define DIM   384
#define SEQ   2048
#define BATCH 8
#define NHEAD 6
#define HD    64
#define MLPD  1536
#define MTOT  (BATCH*SEQ)   // 16384 rows

typedef __attribute__((ext_vector_type(8))) short bf16x8;
typedef __attribute__((ext_vector_type(4))) float f32x4;

static __device__ __forceinline__ float bf2f(unsigned short u){
    union { float f; unsigned int i; } v; v.i = ((unsigned int)u) << 16; return v.f;
}
static __device__ __forceinline__ unsigned short f2bf(float f){
    union { float f; unsigned int i; } v; v.f = f;
    unsigned int r = v.i + 0x7fffu + ((v.i >> 16) & 1u);
    return (unsigned short)(r >> 16);
}
static __device__ __forceinline__ unsigned int asu(float f){
    union { float f; unsigned int i; } v; v.f = f; return v.i;
}
// async global->LDS, 16B per lane; LDS dst = wave-uniform base + lane*16
static __device__ __forceinline__ void gload_lds16(const unsigned short* g, unsigned short* l){
    __builtin_amdgcn_global_load_lds(
        (__attribute__((address_space(1))) void*)(g),
        (__attribute__((address_space(3))) void*)(l), 16, 0, 0);
}
// raw barrier with compiler memory fences
static __device__ __forceinline__ void barx(){
    asm volatile("" ::: "memory");
    __builtin_amdgcn_s_barrier();
    asm volatile("" ::: "memory");
}
#define WAITVM(N) asm volatile("s_waitcnt vmcnt(" #N ")" ::: "memory")

// bijective XCD-chunked remap; REQUIRES gridDim.x % 8 == 0 (all our grids are).
static __device__ __forceinline__ int xcd_lin(){
    return (blockIdx.x & 7) * ((int)gridDim.x >> 3) + ((int)blockIdx.x >> 3);
}

// ---------------- merged: weight transpose+cast (432 blocks) + LN1 (4096 blocks) ----------------
// The two are independent (both read only kernel inputs); merging saves a launch and
// overlaps wt's low-occupancy tail with the BW-bound LN sweep.
__global__ __launch_bounds__(256) void wt_ln_kernel(
    const float* __restrict__ qkv_w, const float* __restrict__ proj_w,
    const float* __restrict__ fc1_w, const float* __restrict__ fc2_w,
    unsigned short* __restrict__ o_qkv, unsigned short* __restrict__ o_prj,
    unsigned short* __restrict__ o_fc1, unsigned short* __restrict__ o_fc2,
    const float* __restrict__ x, const float* __restrict__ g,
    const float* __restrict__ b, unsigned short* __restrict__ ln_out)
{
    __shared__ float tile[64][68];
    int bid = blockIdx.x;
    if (bid >= 432){
        // ---- LN path ----
        int row  = (bid - 432) * 4 + (threadIdx.x >> 6);
        int lane = threadIdx.x & 63;
        const float* xr = x + (size_t)row * DIM;
        float v[6];
#pragma unroll
        for (int p = 0; p < 3; p++){
            float2 t = *(const float2*)(xr + lane * 2 + p * 128);
            v[2*p] = t.x; v[2*p+1] = t.y;
        }
        float s = 0.f, sq = 0.f;
#pragma unroll
        for (int i = 0; i < 6; i++){ s += v[i]; sq += v[i] * v[i]; }
#pragma unroll
        for (int off = 1; off < 64; off <<= 1){
            s  += __shfl_xor(s, off);
            sq += __shfl_xor(sq, off);
        }
        float mu   = s * (1.0f / DIM);
        float var  = sq * (1.0f / DIM) - mu * mu;
        float rstd = rsqrtf(var + 1e-5f);
        unsigned short* orow = ln_out + (size_t)row * DIM;
#pragma unroll
        for (int p = 0; p < 3; p++){
            int c = lane * 2 + p * 128;
            float h0 = (v[2*p]   - mu) * rstd * g[c]   + b[c];
            float h1 = (v[2*p+1] - mu) * rstd * g[c+1] + b[c+1];
            unsigned int pk = (unsigned int)f2bf(h0) | ((unsigned int)f2bf(h1) << 16);
            *(unsigned int*)(orow + c) = pk;
        }
        return;
    }
    // ---- wt path ----
    const float* W; unsigned short* Wt; int K, N, tk, tn;
    if (bid < 108)      { W = qkv_w; Wt = o_qkv; K = 384;  N = 1152; tk = bid/18;        tn = bid%18; }
    else if (bid < 144) { W = proj_w; Wt = o_prj; K = 384;  N = 384;  tk = (bid-108)/6;  tn = (bid-108)%6; }
    else if (bid < 288) { W = fc1_w; Wt = o_fc1; K = 384;  N = 1536; tk = (bid-144)/24; tn = (bid-144)%24; }
    else                { W = fc2_w; Wt = o_fc2; K = 1536; N = 384;  tk = (bid-288)/6;  tn = (bid-288)%6; }
    int t = threadIdx.x;
    int lr = t >> 4, lc = (t & 15) * 4;
#pragma unroll
    for (int p = 0; p < 4; p++){
        float4 v = *(const float4*)(W + (size_t)(tk*64 + p*16 + lr) * N + tn*64 + lc);
        *(float4*)&tile[p*16 + lr][lc] = v;
    }
    __syncthreads();
    int n = t >> 2, k0 = (t & 3) * 16;
    unsigned int w[8];
#pragma unroll
    for (int i = 0; i < 8; i++)
        w[i] = (unsigned int)f2bf(tile[k0 + 2*i][n]) | ((unsigned int)f2bf(tile[k0 + 2*i + 1][n]) << 16);
    unsigned short* dst = Wt + (size_t)(tn*64 + n) * K + tk*64 + k0;
    *(uint4*)(dst)     = make_uint4(w[0], w[1], w[2], w[3]);
    *(uint4*)(dst + 8) = make_uint4(w[4], w[5], w[6], w[7]);
}

// ---------------- layernorm (standalone, for LN2): x f32 [rows][384] -> bf16 out ----------------
__global__ __launch_bounds__(256) void ln_kernel(const float* __restrict__ x,
                                                 const float* __restrict__ g,
                                                 const float* __restrict__ b,
                                                 unsigned short* __restrict__ out){
    int row  = blockIdx.x * 4 + (threadIdx.x >> 6);
    int lane = threadIdx.x & 63;
    const float* xr = x + (size_t)row * DIM;
    float v[6];
#pragma unroll
    for (int p = 0; p < 3; p++){
        float2 t = *(const float2*)(xr + lane * 2 + p * 128);
        v[2*p] = t.x; v[2*p+1] = t.y;
    }
    float s = 0.f, sq = 0.f;
#pragma unroll
    for (int i = 0; i < 6; i++){ s += v[i]; sq += v[i] * v[i]; }
#pragma unroll
    for (int off = 1; off < 64; off <<= 1){
        s  += __shfl_xor(s, off);
        sq += __shfl_xor(sq, off);
    }
    float mu   = s * (1.0f / DIM);
    float var  = sq * (1.0f / DIM) - mu * mu;
    float rstd = rsqrtf(var + 1e-5f);
    unsigned short* orow = out + (size_t)row * DIM;
#pragma unroll
    for (int p = 0; p < 3; p++){
        int c = lane * 2 + p * 128;
        float h0 = (v[2*p]   - mu) * rstd * g[c]   + b[c];
        float h1 = (v[2*p+1] - mu) * rstd * g[c+1] + b[c+1];
        unsigned int pk = (unsigned int)f2bf(h0) | ((unsigned int)f2bf(h1) << 16);
        *(unsigned int*)(orow + c) = pk;
    }
}

// ---------------- GEMM v8 (R10): BM=64 x BN=128, 256 thr, dbuf 48KB, counted vmcnt ----------------
template<int OFF>
static __device__ __forceinline__ void gemm_tile(const unsigned short* smem,
                                                 int wm, int wn, int quad, int l15,
                                                 f32x4 (&acc)[2][4])
{
#pragma unroll
    for (int kk = 0; kk < 2; kk++){
        bf16x8 af[2], bf[4];
#pragma unroll
        for (int i = 0; i < 2; i++){
            int r = wm*32 + i*16 + l15;
            af[i] = *(const bf16x8*)&smem[OFF + r * 64 + (((kk*4 + quad) ^ (l15 & 7)) * 8)];
        }
#pragma unroll
        for (int j = 0; j < 4; j++){
            int r = wn*64 + j*16 + l15;
            bf[j] = *(const bf16x8*)&smem[OFF + 4096 + r * 64 + (((kk*4 + quad) ^ (l15 & 7)) * 8)];
        }
#pragma unroll
        for (int i = 0; i < 2; i++)
#pragma unroll
            for (int j = 0; j < 4; j++)
                acc[i][j] = __builtin_amdgcn_mfma_f32_16x16x32_bf16(af[i], bf[j], acc[i][j], 0, 0, 0);
    }
}

template<int EPI, int NC, int K>
__global__ __launch_bounds__(256, 3) void gemm_kernel(
    const unsigned short* __restrict__ A, const unsigned short* __restrict__ Bt,
    const float* __restrict__ bias, int N,
    const float* __restrict__ resid, float* __restrict__ outf,
    unsigned short* __restrict__ outb,
    unsigned short* __restrict__ qb, unsigned short* __restrict__ kb2,
    unsigned short* __restrict__ vb)
{
    __shared__ __align__(16) unsigned short smem[2 * 12288]; // 48KB
    int t = threadIdx.x;
    int wid = t >> 6, lane = t & 63, quad = lane >> 4, l15 = lane & 15;
    int wm = wid >> 1, wn = wid & 1;
    int lin = xcd_lin();
    int row0 = (lin / NC) * 64, col0 = (lin % NC) * 128;
    int sr = lane >> 3, sc = lane & 7;
    int scl = (sc ^ sr) * 8;                    // global-side swizzled chunk

    // staging: wave wid covers A rows wid*16..+16 (2 gloads), B rows wid*32..+32 (4 gloads)
    const unsigned short* astage[2];
    const unsigned short* bstage[4];
    unsigned short* alds[2];
    unsigned short* blds[4];
#pragma unroll
    for (int jj = 0; jj < 2; jj++){
        int rb = wid * 16 + jj * 8;
        astage[jj] = A + (size_t)(row0 + rb + sr) * K + scl;
        alds[jj]   = (unsigned short*)&smem[rb * 64];
    }
#pragma unroll
    for (int jj = 0; jj < 4; jj++){
        int rb = wid * 32 + jj * 8;
        bstage[jj] = Bt + (size_t)(col0 + rb + sr) * K + scl;
        blds[jj]   = (unsigned short*)&smem[4096 + rb * 64];
    }
    int kc = 0;

#define GSTAGE(LOFF) do { \
    _Pragma("unroll") \
    for (int jj = 0; jj < 2; jj++) \
        gload_lds16(astage[jj] + kc, alds[jj] + (LOFF)); \
    _Pragma("unroll") \
    for (int jj = 0; jj < 4; jj++) \
        gload_lds16(bstage[jj] + kc, blds[jj] + (LOFF)); \
    kc += 64; } while(0)

    f32x4 acc[2][4];
    f32x4 zz = {0.f, 0.f, 0.f, 0.f};
#pragma unroll
    for (int i = 0; i < 2; i++)
#pragma unroll
        for (int j = 0; j < 4; j++) acc[i][j] = zz;

    GSTAGE(0);                                  // tile 0 -> buf0
    constexpr int PAIRS = K / 128;
    for (int p = 0; p < PAIRS - 1; p++){
        GSTAGE(12288);                          // tile 2p+1 -> buf1 (6 more in flight)
        WAITVM(6);                              // tile 2p landed
        barx();
        gemm_tile<0>(smem, wm, wn, quad, l15, acc);
        barx();                                 // all waves done reading buf0
        GSTAGE(0);                              // tile 2p+2 -> buf0
        WAITVM(6);
        barx();
        gemm_tile<12288>(smem, wm, wn, quad, l15, acc);
        barx();
    }
    GSTAGE(12288);                              // last tile -> buf1
    WAITVM(6);
    barx();
    gemm_tile<0>(smem, wm, wn, quad, l15, acc);
    barx();
    WAITVM(0);
    barx();
    gemm_tile<12288>(smem, wm, wn, quad, l15, acc);
#undef GSTAGE

    if (EPI == 0 && col0 >= 768){
        // pure-V block: transpose 64(ns) x 128(d-cols) in LDS, write [d][ns] rows
        __syncthreads();                         // all frag reads done before aliasing smem
        unsigned short* T = smem;                // [128 gc_local][stride 72]
#pragma unroll
        for (int i = 0; i < 2; i++)
#pragma unroll
            for (int j = 0; j < 4; j++){
                int gcl = wn*64 + j*16 + l15;
                float bia = bias[col0 + gcl];
                int nsl0 = wm*32 + i*16 + quad*4;
#pragma unroll
                for (int r = 0; r < 4; r++)
                    T[gcl * 72 + nsl0 + r] = f2bf(acc[i][j][r] + bia);
            }
        __syncthreads();
        int gc = t >> 1, half = t & 1;           // 256 thr: 128 gc rows x 2 halves of 32 ns
        int rem = (col0 - 768) + gc;
        int head = rem >> 6, d = rem & 63;
        int bidx = row0 >> 11, ns0 = row0 & 2047;
        unsigned short* dst = vb + ((size_t)((bidx * NHEAD + head) * 64 + d)) * SEQ + ns0 + half*32;
        const unsigned short* src = T + gc * 72 + half*32;
#pragma unroll
        for (int m = 0; m < 4; m++)
            *(uint4*)(dst + m*8) = *(const uint4*)(src + m*8);
        return;
    }

#pragma unroll
    for (int i = 0; i < 2; i++){
#pragma unroll
        for (int j = 0; j < 4; j++){
            int gr0 = row0 + wm*32 + i*16 + quad*4;
            int gc  = col0 + wn*64 + j*16 + l15;
            float bia = bias[gc];
#pragma unroll
            for (int r = 0; r < 4; r++){
                int gr = gr0 + r;
                float val = acc[i][j][r] + bia;
                if (EPI == 1){
                    outf[(size_t)gr * N + gc] = resid[(size_t)gr * N + gc] + val;
                } else if (EPI == 2){
                    float u = val * (1.0f + 0.044715f * val * val);
                    float e = __builtin_amdgcn_exp2f(u * 2.3025851f);
                    outb[(size_t)gr * N + gc] = f2bf(val * e / (e + 1.0f));
                } else {
                    int trip = gc / 384, remq = gc - trip * 384;
                    int head = remq >> 6, d = remq & 63;
                    int bidx = gr >> 11, ns = gr & 2047;
                    size_t off = ((size_t)(bidx * NHEAD + head) * SEQ + ns) * 64 + d;
                    unsigned short* dstp = (trip == 0) ? qb : kb2;
                    dstp[off] = f2bf(val);
                }
            }
        }
    }
}

// ---------------- flash attention v10: R8 structure, sacc MFMAs -> VALU row-sum ----------------
// The 4 ones-MFMAs per tile (row-sum of exp) are replaced by per-lane f32 adds in the exp
// phase (kv slices are quad-partitioned, q=l15 is lane-local) + two shfl_xor after the loop.
template<int LOFF>
static __device__ __forceinline__ void attn_tile(
    const bf16x8 (&qf)[2][2],
    const unsigned short* const (&kf_ptr)[4][2],
    const unsigned short* const (&vf_ptr)[2][4],
    const unsigned short* const (&pf_ptr)[2][2],
    uint2* const (&pw_ptr)[2][4],
    float (&ssum)[2], f32x4 (&oacc)[2][4])
{
    const f32x4 zz = {0.f, 0.f, 0.f, 0.f};
    f32x4 st[2][4];
    __builtin_amdgcn_s_setprio(1);
#pragma unroll
    for (int n = 0; n < 4; n++){
        bf16x8 kf0 = *(const bf16x8*)(kf_ptr[n][0] + LOFF);
        bf16x8 kf1 = *(const bf16x8*)(kf_ptr[n][1] + LOFF);
#pragma unroll
        for (int h = 0; h < 2; h++){
            f32x4 z = __builtin_amdgcn_mfma_f32_16x16x32_bf16(kf0, qf[h][0], zz, 0, 0, 0);
            st[h][n] = __builtin_amdgcn_mfma_f32_16x16x32_bf16(kf1, qf[h][1], z, 0, 0, 0);
        }
    }
    __builtin_amdgcn_s_setprio(0);
#pragma unroll
    for (int h = 0; h < 2; h++){
#pragma unroll
        for (int n = 0; n < 4; n++){
            float p0 = __builtin_amdgcn_exp2f(st[h][n][0]);
            float p1 = __builtin_amdgcn_exp2f(st[h][n][1]);
            float p2 = __builtin_amdgcn_exp2f(st[h][n][2]);
            float p3 = __builtin_amdgcn_exp2f(st[h][n][3]);
            ssum[h] += (p0 + p1) + (p2 + p3);
            unsigned int w0 = __builtin_amdgcn_perm(asu(p1), asu(p0), 0x07060302u);
            unsigned int w1 = __builtin_amdgcn_perm(asu(p3), asu(p2), 0x07060302u);
            *pw_ptr[h][n] = make_uint2(w0, w1);
        }
    }
    asm volatile("s_waitcnt lgkmcnt(0)" ::: "memory");  // wave-private P w->r
    __builtin_amdgcn_s_setprio(1);
#pragma unroll
    for (int c = 0; c < 2; c++){
        bf16x8 pf[2];
#pragma unroll
        for (int h = 0; h < 2; h++)
            pf[h] = *(const bf16x8*)pf_ptr[c][h];
#pragma unroll
        for (int dn = 0; dn < 4; dn++){
            bf16x8 vf = *(const bf16x8*)(vf_ptr[c][dn] + LOFF);
            oacc[0][dn] = __builtin_amdgcn_mfma_f32_16x16x32_bf16(vf, pf[0], oacc[0][dn], 0, 0, 0);
            oacc[1][dn] = __builtin_amdgcn_mfma_f32_16x16x32_bf16(vf, pf[1], oacc[1][dn], 0, 0, 0);
        }
    }
    __builtin_amdgcn_s_setprio(0);
}

__global__ __launch_bounds__(256, 3) void attn_kernel(const unsigned short* __restrict__ Q,
                                                      const unsigned short* __restrict__ Kb,
                                                      const unsigned short* __restrict__ Vt,
                                                      unsigned short* __restrict__ O){
    __shared__ __align__(16) unsigned short smem[16384 + 4*2048]; // 48KB

    int lin = xcd_lin();                         // contiguous lin = same head (L2 K/V reuse)
    int qt = lin & 15, bh = lin >> 4;
    int t = threadIdx.x, wid = t >> 6, lane = t & 63, quad = lane >> 4, l15 = lane & 15;
    int l7 = l15 & 7;
    int q0 = qt * 128 + wid * 32;
    const unsigned short* Qp = Q  + (size_t)bh * SEQ * 64;
    const unsigned short* Kp = Kb + (size_t)bh * SEQ * 64;
    const unsigned short* Vp = Vt + (size_t)bh * 64 * SEQ;
    int sr = lane >> 3, sc = lane & 7;
    int scl = (sc ^ sr) * 8;

    const float QSCALE = 0.125f * 1.44269504f;  // fold 1/sqrt(64) and log2(e)
    bf16x8 qf[2][2];
#pragma unroll
    for (int h = 0; h < 2; h++){
#pragma unroll
        for (int c = 0; c < 2; c++){
            union { uint4 u; unsigned short s[8]; } cv;
            cv.u = *(const uint4*)(Qp + (size_t)(q0 + h*16 + l15) * 64 + c * 32 + quad * 8);
            bf16x8 f;
#pragma unroll
            for (int j = 0; j < 8; j++) f[j] = (short)f2bf(bf2f(cv.s[j]) * QSCALE);
            qf[h][c] = f;
        }
    }

    f32x4 oacc[2][4];
    float ssum[2] = {0.f, 0.f};
    f32x4 zz = {0.f, 0.f, 0.f, 0.f};
#pragma unroll
    for (int h = 0; h < 2; h++)
#pragma unroll
        for (int dn = 0; dn < 4; dn++) oacc[h][dn] = zz;
    unsigned short* P = &smem[16384 + wid * 2048];

    const unsigned short* kf_ptr[4][2];
#pragma unroll
    for (int n = 0; n < 4; n++){
        int kv = n * 16 + l15;
        kf_ptr[n][0] = &smem[kv * 64 + ((quad       ^ (kv & 7)) * 8)];
        kf_ptr[n][1] = &smem[kv * 64 + (((4 + quad) ^ (kv & 7)) * 8)];
    }
    const unsigned short* vf_ptr[2][4];
#pragma unroll
    for (int c = 0; c < 2; c++)
#pragma unroll
        for (int dn = 0; dn < 4; dn++){
            int d = dn * 16 + l15;
            vf_ptr[c][dn] = &smem[4096 + d * 64 + (((c*4 + quad) ^ (d & 7)) * 8)];
        }
    const unsigned short* pf_ptr[2][2];
#pragma unroll
    for (int c = 0; c < 2; c++)
#pragma unroll
        for (int h = 0; h < 2; h++)
            pf_ptr[c][h] = P + (h*16 + l15) * 64 + (((c*4 + quad) ^ l7) * 8);
    uint2* pw_ptr[2][4];
#pragma unroll
    for (int h = 0; h < 2; h++)
#pragma unroll
        for (int n = 0; n < 4; n++){
            int qloc = h * 16 + l15;
            int chunk = n * 2 + (quad >> 1);
            pw_ptr[h][n] = (uint2*)(P + qloc * 64 + ((chunk ^ l7) * 8) + (quad & 1) * 4);
        }
    const unsigned short* kstage[2];
    const unsigned short* vstage[2];
    unsigned short* klds[2];
    unsigned short* vlds[2];
#pragma unroll
    for (int jj = 0; jj < 2; jj++){
        int rb = wid * 16 + jj * 8;
        kstage[jj] = Kp + (size_t)(rb + sr) * 64 + scl;
        vstage[jj] = Vp + (size_t)(rb + sr) * SEQ + scl;
        klds[jj] = &smem[rb * 64];
        vlds[jj] = &smem[4096 + rb * 64];
    }

#define AISSUE(BOFF) do { \
    _Pragma("unroll") \
    for (int jj = 0; jj < 2; jj++){ \
        gload_lds16(kstage[jj], klds[jj] + (BOFF)); \
        gload_lds16(vstage[jj], vlds[jj] + (BOFF)); \
        kstage[jj] += 64 * 64; \
        vstage[jj] += 64; \
    } } while(0)

    AISSUE(0);                                   // tile 0 -> buf0
    for (int p = 0; p < SEQ/128 - 1; p++){       // 15 steady-state pairs
        AISSUE(8192);                            // tile 2p+1 -> buf1 (4 more in flight)
        WAITVM(4);                               // tile 2p landed
        barx();
        attn_tile<0>(qf, kf_ptr, vf_ptr, pf_ptr, pw_ptr, ssum, oacc);
        barx();                                  // all waves done reading buf0
        AISSUE(0);                               // tile 2p+2 -> buf0
        WAITVM(4);
        barx();
        attn_tile<8192>(qf, kf_ptr, vf_ptr, pf_ptr, pw_ptr, ssum, oacc);
        barx();
    }
    AISSUE(8192);                                // tile 31 -> buf1
    WAITVM(4);
    barx();
    attn_tile<0>(qf, kf_ptr, vf_ptr, pf_ptr, pw_ptr, ssum, oacc);
    barx();
    WAITVM(0);
    barx();
    attn_tile<8192>(qf, kf_ptr, vf_ptr, pf_ptr, pw_ptr, ssum, oacc);
#undef AISSUE

    // cross-quad reduction of the per-lane partial row-sums (kv quad-slices)
#pragma unroll
    for (int h = 0; h < 2; h++){
        ssum[h] += __shfl_xor(ssum[h], 16);
        ssum[h] += __shfl_xor(ssum[h], 32);
    }

    int b = bh / NHEAD, hh = bh - b * NHEAD;
#pragma unroll
    for (int h = 0; h < 2; h++){
        float rd = 1.0f / ssum[h];
        size_t row = (size_t)(b * SEQ + q0 + h*16 + l15);
#pragma unroll
        for (int dn = 0; dn < 4; dn++){
            float v0 = oacc[h][dn][0] * rd, v1 = oacc[h][dn][1] * rd;
            float v2 = oacc[h][dn][2] * rd, v3 = oacc[h][dn][3] * rd;
            unsigned int w0 = (unsigned int)f2bf(v0) | ((unsigned int)f2bf(v1) << 16);
            unsigned int w1 = (unsigned int)f2bf(v2) | ((unsigned int)f2bf(v3) << 16);
            *(uint2*)(O + row * DIM + hh * 64 + dn * 16 + quad * 4) = make_uint2(w0, w1);
        }
    }
}

// ---------------- launcher ----------------
extern "C" void kernel_launch(void* const* d_in, const int* in_sizes, int n_in,
                              void* d_out, int out_size, void* d_ws, size_t ws_size,
                              hipStream_t stream){
    const float* x      = (const float*)d_in[0];
    const float* ln1_g  = (const float*)d_in[1];
    const float* ln1_b  = (const float*)d_in[2];
    const float* qkv_w  = (const float*)d_in[3];
    const float* qkv_b  = (const float*)d_in[4];
    const float* proj_w = (const float*)d_in[5];
    const float* proj_b = (const float*)d_in[6];
    const float* ln2_g  = (const float*)d_in[7];
    const float* ln2_b  = (const float*)d_in[8];
    const float* fc1_w  = (const float*)d_in[9];
    const float* fc1_b  = (const float*)d_in[10];
    const float* fc2_w  = (const float*)d_in[11];
    const float* fc2_b  = (const float*)d_in[12];
    float* out = (float*)d_out;

    char* p = (char*)d_ws;
    auto take = [&](size_t n){ char* r = p; p += (n + 255) & ~(size_t)255; return r; };
    unsigned short* wt_qkv = (unsigned short*)take((size_t)1152 * 384 * 2);
    unsigned short* wt_prj = (unsigned short*)take((size_t)384 * 384 * 2);
    unsigned short* wt_fc1 = (unsigned short*)take((size_t)1536 * 384 * 2);
    unsigned short* wt_fc2 = (unsigned short*)take((size_t)384 * 1536 * 2);
    unsigned short* rbig   = (unsigned short*)take((size_t)MTOT * 4 * DIM * 2); // h1|q|k|v, later hm
    unsigned short* h2     = (unsigned short*)take((size_t)MTOT * DIM * 2);     // ln2 out
    float*          x1     = (float*)take((size_t)MTOT * DIM * 4);

    unsigned short* h1     = rbig;
    unsigned short* qb     = rbig + (size_t)MTOT * DIM;
    unsigned short* kb     = qb   + (size_t)MTOT * DIM;
    unsigned short* vb     = kb   + (size_t)MTOT * DIM;   // [bh][64][SEQ], written by qkv gemm
    unsigned short* attn_o = rbig;   // reuses h1 (dead after QKV gemm)
    unsigned short* hm     = rbig;   // reuses h1+qkv (dead after proj)

    wt_ln_kernel<<<dim3(432 + MTOT/4), 256, 0, stream>>>(qkv_w, proj_w, fc1_w, fc2_w,
                                                         wt_qkv, wt_prj, wt_fc1, wt_fc2,
                                                         x, ln1_g, ln1_b, h1);
    gemm_kernel<0,9,384><<<dim3(2304), 256, 0, stream>>>(h1, wt_qkv, qkv_b, 1152,
                                                     nullptr, nullptr, nullptr, qb, kb, vb);
    attn_kernel<<<dim3(768), 256, 0, stream>>>(qb, kb, vb, attn_o);
    gemm_kernel<1,3,384><<<dim3(768), 256, 0, stream>>>(attn_o, wt_prj, proj_b, 384,
                                                    x, x1, nullptr, nullptr, nullptr, nullptr);
    ln_kernel<<<dim3(MTOT/4), 256, 0, stream>>>(x1, ln2_g, ln2_b, h2);
    gemm_kernel<2,12,384><<<dim3(3072), 256, 0, stream>>>(h2, wt_fc1, fc1_b, 1536,
                                                      nullptr, nullptr, hm, nullptr, nullptr, nullptr);
    gemm_kernel<1,3,1536><<<dim3(768), 256, 0, stream>>>(hm, wt_fc2, fc2_b, 384,
                                                    x1, out, nullptr, nullptr, nullptr, nullptr);
}

// Round 12
// 260.174 us; speedup vs baseline: 1.0486x; 1.0486x over previous
//
#include <hip/hip_runtime.h>
#include <hip/hip_bf16.h>

#define DIM   384
#define SEQ   2048
#define BATCH 8
#define NHEAD 6
#define HD    64
#define MLPD  1536
#define MTOT  (BATCH*SEQ)   // 16384 rows

typedef __attribute__((ext_vector_type(8))) short bf16x8;
typedef __attribute__((ext_vector_type(4))) float f32x4;

static __device__ __forceinline__ float bf2f(unsigned short u){
    union { float f; unsigned int i; } v; v.i = ((unsigned int)u) << 16; return v.f;
}
static __device__ __forceinline__ unsigned short f2bf(float f){
    union { float f; unsigned int i; } v; v.f = f;
    unsigned int r = v.i + 0x7fffu + ((v.i >> 16) & 1u);
    return (unsigned short)(r >> 16);
}
static __device__ __forceinline__ unsigned int asu(float f){
    union { float f; unsigned int i; } v; v.f = f; return v.i;
}
// async global->LDS, 16B per lane; LDS dst = wave-uniform base + lane*16
static __device__ __forceinline__ void gload_lds16(const unsigned short* g, unsigned short* l){
    __builtin_amdgcn_global_load_lds(
        (__attribute__((address_space(1))) void*)(g),
        (__attribute__((address_space(3))) void*)(l), 16, 0, 0);
}
// raw barrier with compiler memory fences
static __device__ __forceinline__ void barx(){
    asm volatile("" ::: "memory");
    __builtin_amdgcn_s_barrier();
    asm volatile("" ::: "memory");
}
#define WAITVM(N) asm volatile("s_waitcnt vmcnt(" #N ")" ::: "memory")

// bijective XCD-chunked remap; REQUIRES gridDim.x % 8 == 0 (all our grids are).
static __device__ __forceinline__ int xcd_lin(){
    return (blockIdx.x & 7) * ((int)gridDim.x >> 3) + ((int)blockIdx.x >> 3);
}

// ---------------- merged: weight transpose+cast (432 blocks) + LN1 (4096 blocks) ----------------
__global__ __launch_bounds__(256) void wt_ln_kernel(
    const float* __restrict__ qkv_w, const float* __restrict__ proj_w,
    const float* __restrict__ fc1_w, const float* __restrict__ fc2_w,
    unsigned short* __restrict__ o_qkv, unsigned short* __restrict__ o_prj,
    unsigned short* __restrict__ o_fc1, unsigned short* __restrict__ o_fc2,
    const float* __restrict__ x, const float* __restrict__ g,
    const float* __restrict__ b, unsigned short* __restrict__ ln_out)
{
    __shared__ float tile[64][68];
    int bid = blockIdx.x;
    if (bid >= 432){
        // ---- LN path ----
        int row  = (bid - 432) * 4 + (threadIdx.x >> 6);
        int lane = threadIdx.x & 63;
        const float* xr = x + (size_t)row * DIM;
        float v[6];
#pragma unroll
        for (int p = 0; p < 3; p++){
            float2 t = *(const float2*)(xr + lane * 2 + p * 128);
            v[2*p] = t.x; v[2*p+1] = t.y;
        }
        float s = 0.f, sq = 0.f;
#pragma unroll
        for (int i = 0; i < 6; i++){ s += v[i]; sq += v[i] * v[i]; }
#pragma unroll
        for (int off = 1; off < 64; off <<= 1){
            s  += __shfl_xor(s, off);
            sq += __shfl_xor(sq, off);
        }
        float mu   = s * (1.0f / DIM);
        float var  = sq * (1.0f / DIM) - mu * mu;
        float rstd = rsqrtf(var + 1e-5f);
        unsigned short* orow = ln_out + (size_t)row * DIM;
#pragma unroll
        for (int p = 0; p < 3; p++){
            int c = lane * 2 + p * 128;
            float h0 = (v[2*p]   - mu) * rstd * g[c]   + b[c];
            float h1 = (v[2*p+1] - mu) * rstd * g[c+1] + b[c+1];
            unsigned int pk = (unsigned int)f2bf(h0) | ((unsigned int)f2bf(h1) << 16);
            *(unsigned int*)(orow + c) = pk;
        }
        return;
    }
    // ---- wt path ----
    const float* W; unsigned short* Wt; int K, N, tk, tn;
    if (bid < 108)      { W = qkv_w; Wt = o_qkv; K = 384;  N = 1152; tk = bid/18;        tn = bid%18; }
    else if (bid < 144) { W = proj_w; Wt = o_prj; K = 384;  N = 384;  tk = (bid-108)/6;  tn = (bid-108)%6; }
    else if (bid < 288) { W = fc1_w; Wt = o_fc1; K = 384;  N = 1536; tk = (bid-144)/24; tn = (bid-144)%24; }
    else                { W = fc2_w; Wt = o_fc2; K = 1536; N = 384;  tk = (bid-288)/6;  tn = (bid-288)%6; }
    int t = threadIdx.x;
    int lr = t >> 4, lc = (t & 15) * 4;
#pragma unroll
    for (int p = 0; p < 4; p++){
        float4 v = *(const float4*)(W + (size_t)(tk*64 + p*16 + lr) * N + tn*64 + lc);
        *(float4*)&tile[p*16 + lr][lc] = v;
    }
    __syncthreads();
    int n = t >> 2, k0 = (t & 3) * 16;
    unsigned int w[8];
#pragma unroll
    for (int i = 0; i < 8; i++)
        w[i] = (unsigned int)f2bf(tile[k0 + 2*i][n]) | ((unsigned int)f2bf(tile[k0 + 2*i + 1][n]) << 16);
    unsigned short* dst = Wt + (size_t)(tn*64 + n) * K + tk*64 + k0;
    *(uint4*)(dst)     = make_uint4(w[0], w[1], w[2], w[3]);
    *(uint4*)(dst + 8) = make_uint4(w[4], w[5], w[6], w[7]);
}

// ---------------- layernorm (standalone, for LN2): x f32 [rows][384] -> bf16 out ----------------
__global__ __launch_bounds__(256) void ln_kernel(const float* __restrict__ x,
                                                 const float* __restrict__ g,
                                                 const float* __restrict__ b,
                                                 unsigned short* __restrict__ out){
    int row  = blockIdx.x * 4 + (threadIdx.x >> 6);
    int lane = threadIdx.x & 63;
    const float* xr = x + (size_t)row * DIM;
    float v[6];
#pragma unroll
    for (int p = 0; p < 3; p++){
        float2 t = *(const float2*)(xr + lane * 2 + p * 128);
        v[2*p] = t.x; v[2*p+1] = t.y;
    }
    float s = 0.f, sq = 0.f;
#pragma unroll
    for (int i = 0; i < 6; i++){ s += v[i]; sq += v[i] * v[i]; }
#pragma unroll
    for (int off = 1; off < 64; off <<= 1){
        s  += __shfl_xor(s, off);
        sq += __shfl_xor(sq, off);
    }
    float mu   = s * (1.0f / DIM);
    float var  = sq * (1.0f / DIM) - mu * mu;
    float rstd = rsqrtf(var + 1e-5f);
    unsigned short* orow = out + (size_t)row * DIM;
#pragma unroll
    for (int p = 0; p < 3; p++){
        int c = lane * 2 + p * 128;
        float h0 = (v[2*p]   - mu) * rstd * g[c]   + b[c];
        float h1 = (v[2*p+1] - mu) * rstd * g[c+1] + b[c+1];
        unsigned int pk = (unsigned int)f2bf(h0) | ((unsigned int)f2bf(h1) << 16);
        *(unsigned int*)(orow + c) = pk;
    }
}

// ---------------- GEMM v8 (R10 proven): BM=64 x BN=128, 256 thr, dbuf 48KB, counted vmcnt ----------------
template<int OFF>
static __device__ __forceinline__ void gemm_tile(const unsigned short* smem,
                                                 int wm, int wn, int quad, int l15,
                                                 f32x4 (&acc)[2][4])
{
#pragma unroll
    for (int kk = 0; kk < 2; kk++){
        bf16x8 af[2], bf[4];
#pragma unroll
        for (int i = 0; i < 2; i++){
            int r = wm*32 + i*16 + l15;
            af[i] = *(const bf16x8*)&smem[OFF + r * 64 + (((kk*4 + quad) ^ (l15 & 7)) * 8)];
        }
#pragma unroll
        for (int j = 0; j < 4; j++){
            int r = wn*64 + j*16 + l15;
            bf[j] = *(const bf16x8*)&smem[OFF + 4096 + r * 64 + (((kk*4 + quad) ^ (l15 & 7)) * 8)];
        }
#pragma unroll
        for (int i = 0; i < 2; i++)
#pragma unroll
            for (int j = 0; j < 4; j++)
                acc[i][j] = __builtin_amdgcn_mfma_f32_16x16x32_bf16(af[i], bf[j], acc[i][j], 0, 0, 0);
    }
}

template<int EPI, int NC, int K>
__global__ __launch_bounds__(256, 3) void gemm_kernel(
    const unsigned short* __restrict__ A, const unsigned short* __restrict__ Bt,
    const float* __restrict__ bias, int N,
    const float* __restrict__ resid, float* __restrict__ outf,
    unsigned short* __restrict__ outb,
    unsigned short* __restrict__ qb, unsigned short* __restrict__ kb2,
    unsigned short* __restrict__ vb)
{
    __shared__ __align__(16) unsigned short smem[2 * 12288]; // 48KB
    int t = threadIdx.x;
    int wid = t >> 6, lane = t & 63, quad = lane >> 4, l15 = lane & 15;
    int wm = wid >> 1, wn = wid & 1;
    int lin = xcd_lin();
    int row0 = (lin / NC) * 64, col0 = (lin % NC) * 128;
    int sr = lane >> 3, sc = lane & 7;
    int scl = (sc ^ sr) * 8;                    // global-side swizzled chunk

    // staging: wave wid covers A rows wid*16..+16 (2 gloads), B rows wid*32..+32 (4 gloads)
    const unsigned short* astage[2];
    const unsigned short* bstage[4];
    unsigned short* alds[2];
    unsigned short* blds[4];
#pragma unroll
    for (int jj = 0; jj < 2; jj++){
        int rb = wid * 16 + jj * 8;
        astage[jj] = A + (size_t)(row0 + rb + sr) * K + scl;
        alds[jj]   = (unsigned short*)&smem[rb * 64];
    }
#pragma unroll
    for (int jj = 0; jj < 4; jj++){
        int rb = wid * 32 + jj * 8;
        bstage[jj] = Bt + (size_t)(col0 + rb + sr) * K + scl;
        blds[jj]   = (unsigned short*)&smem[4096 + rb * 64];
    }
    int kc = 0;

#define GSTAGE(LOFF) do { \
    _Pragma("unroll") \
    for (int jj = 0; jj < 2; jj++) \
        gload_lds16(astage[jj] + kc, alds[jj] + (LOFF)); \
    _Pragma("unroll") \
    for (int jj = 0; jj < 4; jj++) \
        gload_lds16(bstage[jj] + kc, blds[jj] + (LOFF)); \
    kc += 64; } while(0)

    f32x4 acc[2][4];
    f32x4 zz = {0.f, 0.f, 0.f, 0.f};
#pragma unroll
    for (int i = 0; i < 2; i++)
#pragma unroll
        for (int j = 0; j < 4; j++) acc[i][j] = zz;

    GSTAGE(0);                                  // tile 0 -> buf0
    constexpr int PAIRS = K / 128;
    for (int p = 0; p < PAIRS - 1; p++){
        GSTAGE(12288);                          // tile 2p+1 -> buf1 (6 more in flight)
        WAITVM(6);                              // tile 2p landed
        barx();
        gemm_tile<0>(smem, wm, wn, quad, l15, acc);
        barx();                                 // all waves done reading buf0
        GSTAGE(0);                              // tile 2p+2 -> buf0
        WAITVM(6);
        barx();
        gemm_tile<12288>(smem, wm, wn, quad, l15, acc);
        barx();
    }
    GSTAGE(12288);                              // last tile -> buf1
    WAITVM(6);
    barx();
    gemm_tile<0>(smem, wm, wn, quad, l15, acc);
    barx();
    WAITVM(0);
    barx();
    gemm_tile<12288>(smem, wm, wn, quad, l15, acc);
#undef GSTAGE

    if (EPI == 0 && col0 >= 768){
        // pure-V block: transpose 64(ns) x 128(d-cols) in LDS, write [d][ns] rows
        __syncthreads();                         // all frag reads done before aliasing smem
        unsigned short* T = smem;                // [128 gc_local][stride 72]
#pragma unroll
        for (int i = 0; i < 2; i++)
#pragma unroll
            for (int j = 0; j < 4; j++){
                int gcl = wn*64 + j*16 + l15;
                float bia = bias[col0 + gcl];
                int nsl0 = wm*32 + i*16 + quad*4;
#pragma unroll
                for (int r = 0; r < 4; r++)
                    T[gcl * 72 + nsl0 + r] = f2bf(acc[i][j][r] + bia);
            }
        __syncthreads();
        int gc = t >> 1, half = t & 1;           // 256 thr: 128 gc rows x 2 halves of 32 ns
        int rem = (col0 - 768) + gc;
        int head = rem >> 6, d = rem & 63;
        int bidx = row0 >> 11, ns0 = row0 & 2047;
        unsigned short* dst = vb + ((size_t)((bidx * NHEAD + head) * 64 + d)) * SEQ + ns0 + half*32;
        const unsigned short* src = T + gc * 72 + half*32;
#pragma unroll
        for (int m = 0; m < 4; m++)
            *(uint4*)(dst + m*8) = *(const uint4*)(src + m*8);
        return;
    }

#pragma unroll
    for (int i = 0; i < 2; i++){
#pragma unroll
        for (int j = 0; j < 4; j++){
            int gr0 = row0 + wm*32 + i*16 + quad*4;
            int gc  = col0 + wn*64 + j*16 + l15;
            float bia = bias[gc];
#pragma unroll
            for (int r = 0; r < 4; r++){
                int gr = gr0 + r;
                float val = acc[i][j][r] + bia;
                if (EPI == 1){
                    outf[(size_t)gr * N + gc] = resid[(size_t)gr * N + gc] + val;
                } else if (EPI == 2){
                    float u = val * (1.0f + 0.044715f * val * val);
                    float e = __builtin_amdgcn_exp2f(u * 2.3025851f);
                    outb[(size_t)gr * N + gc] = f2bf(val * e / (e + 1.0f));
                } else {
                    int trip = gc / 384, remq = gc - trip * 384;
                    int head = remq >> 6, d = remq & 63;
                    int bidx = gr >> 11, ns = gr & 2047;
                    size_t off = ((size_t)(bidx * NHEAD + head) * SEQ + ns) * 64 + d;
                    unsigned short* dstp = (trip == 0) ? qb : kb2;
                    dstp[off] = f2bf(val);
                }
            }
        }
    }
}

// ---------------- flash attention v9 (R8/R10 proven): dbuf K/V + counted vmcnt + setprio ----------------
template<int LOFF>
static __device__ __forceinline__ void attn_tile(
    const bf16x8 (&qf)[2][2], const bf16x8& ones,
    const unsigned short* const (&kf_ptr)[4][2],
    const unsigned short* const (&vf_ptr)[2][4],
    const unsigned short* const (&pf_ptr)[2][2],
    uint2* const (&pw_ptr)[2][4],
    f32x4 (&sacc)[2], f32x4 (&oacc)[2][4])
{
    const f32x4 zz = {0.f, 0.f, 0.f, 0.f};
    f32x4 st[2][4];
    __builtin_amdgcn_s_setprio(1);
#pragma unroll
    for (int n = 0; n < 4; n++){
        bf16x8 kf0 = *(const bf16x8*)(kf_ptr[n][0] + LOFF);
        bf16x8 kf1 = *(const bf16x8*)(kf_ptr[n][1] + LOFF);
#pragma unroll
        for (int h = 0; h < 2; h++){
            f32x4 z = __builtin_amdgcn_mfma_f32_16x16x32_bf16(kf0, qf[h][0], zz, 0, 0, 0);
            st[h][n] = __builtin_amdgcn_mfma_f32_16x16x32_bf16(kf1, qf[h][1], z, 0, 0, 0);
        }
    }
    __builtin_amdgcn_s_setprio(0);
#pragma unroll
    for (int h = 0; h < 2; h++){
#pragma unroll
        for (int n = 0; n < 4; n++){
            float p0 = __builtin_amdgcn_exp2f(st[h][n][0]);
            float p1 = __builtin_amdgcn_exp2f(st[h][n][1]);
            float p2 = __builtin_amdgcn_exp2f(st[h][n][2]);
            float p3 = __builtin_amdgcn_exp2f(st[h][n][3]);
            unsigned int w0 = __builtin_amdgcn_perm(asu(p1), asu(p0), 0x07060302u);
            unsigned int w1 = __builtin_amdgcn_perm(asu(p3), asu(p2), 0x07060302u);
            *pw_ptr[h][n] = make_uint2(w0, w1);
        }
    }
    asm volatile("s_waitcnt lgkmcnt(0)" ::: "memory");  // wave-private P w->r
    __builtin_amdgcn_s_setprio(1);
#pragma unroll
    for (int c = 0; c < 2; c++){
        bf16x8 pf[2];
#pragma unroll
        for (int h = 0; h < 2; h++)
            pf[h] = *(const bf16x8*)pf_ptr[c][h];
        sacc[0] = __builtin_amdgcn_mfma_f32_16x16x32_bf16(ones, pf[0], sacc[0], 0, 0, 0);
        sacc[1] = __builtin_amdgcn_mfma_f32_16x16x32_bf16(ones, pf[1], sacc[1], 0, 0, 0);
#pragma unroll
        for (int dn = 0; dn < 4; dn++){
            bf16x8 vf = *(const bf16x8*)(vf_ptr[c][dn] + LOFF);
            oacc[0][dn] = __builtin_amdgcn_mfma_f32_16x16x32_bf16(vf, pf[0], oacc[0][dn], 0, 0, 0);
            oacc[1][dn] = __builtin_amdgcn_mfma_f32_16x16x32_bf16(vf, pf[1], oacc[1][dn], 0, 0, 0);
        }
    }
    __builtin_amdgcn_s_setprio(0);
}

__global__ __launch_bounds__(256, 3) void attn_kernel(const unsigned short* __restrict__ Q,
                                                      const unsigned short* __restrict__ Kb,
                                                      const unsigned short* __restrict__ Vt,
                                                      unsigned short* __restrict__ O){
    __shared__ __align__(16) unsigned short smem[16384 + 4*2048]; // 48KB

    int lin = xcd_lin();                         // contiguous lin = same head (L2 K/V reuse)
    int qt = lin & 15, bh = lin >> 4;
    int t = threadIdx.x, wid = t >> 6, lane = t & 63, quad = lane >> 4, l15 = lane & 15;
    int l7 = l15 & 7;
    int q0 = qt * 128 + wid * 32;
    const unsigned short* Qp = Q  + (size_t)bh * SEQ * 64;
    const unsigned short* Kp = Kb + (size_t)bh * SEQ * 64;
    const unsigned short* Vp = Vt + (size_t)bh * 64 * SEQ;
    int sr = lane >> 3, sc = lane & 7;
    int scl = (sc ^ sr) * 8;

    const float QSCALE = 0.125f * 1.44269504f;  // fold 1/sqrt(64) and log2(e)
    bf16x8 qf[2][2];
#pragma unroll
    for (int h = 0; h < 2; h++){
#pragma unroll
        for (int c = 0; c < 2; c++){
            union { uint4 u; unsigned short s[8]; } cv;
            cv.u = *(const uint4*)(Qp + (size_t)(q0 + h*16 + l15) * 64 + c * 32 + quad * 8);
            bf16x8 f;
#pragma unroll
            for (int j = 0; j < 8; j++) f[j] = (short)f2bf(bf2f(cv.s[j]) * QSCALE);
            qf[h][c] = f;
        }
    }

    bf16x8 ones;
#pragma unroll
    for (int j = 0; j < 8; j++) ones[j] = (short)0x3F80;    // bf16 1.0

    f32x4 oacc[2][4], sacc[2];
    f32x4 zz = {0.f, 0.f, 0.f, 0.f};
#pragma unroll
    for (int h = 0; h < 2; h++){
        sacc[h] = zz;
#pragma unroll
        for (int dn = 0; dn < 4; dn++) oacc[h][dn] = zz;
    }
    unsigned short* P = &smem[16384 + wid * 2048];

    const unsigned short* kf_ptr[4][2];
#pragma unroll
    for (int n = 0; n < 4; n++){
        int kv = n * 16 + l15;
        kf_ptr[n][0] = &smem[kv * 64 + ((quad       ^ (kv & 7)) * 8)];
        kf_ptr[n][1] = &smem[kv * 64 + (((4 + quad) ^ (kv & 7)) * 8)];
    }
    const unsigned short* vf_ptr[2][4];
#pragma unroll
    for (int c = 0; c < 2; c++)
#pragma unroll
        for (int dn = 0; dn < 4; dn++){
            int d = dn * 16 + l15;
            vf_ptr[c][dn] = &smem[4096 + d * 64 + (((c*4 + quad) ^ (d & 7)) * 8)];
        }
    const unsigned short* pf_ptr[2][2];
#pragma unroll
    for (int c = 0; c < 2; c++)
#pragma unroll
        for (int h = 0; h < 2; h++)
            pf_ptr[c][h] = P + (h*16 + l15) * 64 + (((c*4 + quad) ^ l7) * 8);
    uint2* pw_ptr[2][4];
#pragma unroll
    for (int h = 0; h < 2; h++)
#pragma unroll
        for (int n = 0; n < 4; n++){
            int qloc = h * 16 + l15;
            int chunk = n * 2 + (quad >> 1);
            pw_ptr[h][n] = (uint2*)(P + qloc * 64 + ((chunk ^ l7) * 8) + (quad & 1) * 4);
        }
    const unsigned short* kstage[2];
    const unsigned short* vstage[2];
    unsigned short* klds[2];
    unsigned short* vlds[2];
#pragma unroll
    for (int jj = 0; jj < 2; jj++){
        int rb = wid * 16 + jj * 8;
        kstage[jj] = Kp + (size_t)(rb + sr) * 64 + scl;
        vstage[jj] = Vp + (size_t)(rb + sr) * SEQ + scl;
        klds[jj] = &smem[rb * 64];
        vlds[jj] = &smem[4096 + rb * 64];
    }

#define AISSUE(BOFF) do { \
    _Pragma("unroll") \
    for (int jj = 0; jj < 2; jj++){ \
        gload_lds16(kstage[jj], klds[jj] + (BOFF)); \
        gload_lds16(vstage[jj], vlds[jj] + (BOFF)); \
        kstage[jj] += 64 * 64; \
        vstage[jj] += 64; \
    } } while(0)

    AISSUE(0);                                   // tile 0 -> buf0
    for (int p = 0; p < SEQ/128 - 1; p++){       // 15 steady-state pairs
        AISSUE(8192);                            // tile 2p+1 -> buf1 (4 more in flight)
        WAITVM(4);                               // tile 2p landed
        barx();
        attn_tile<0>(qf, ones, kf_ptr, vf_ptr, pf_ptr, pw_ptr, sacc, oacc);
        barx();                                  // all waves done reading buf0
        AISSUE(0);                               // tile 2p+2 -> buf0
        WAITVM(4);
        barx();
        attn_tile<8192>(qf, ones, kf_ptr, vf_ptr, pf_ptr, pw_ptr, sacc, oacc);
        barx();
    }
    AISSUE(8192);                                // tile 31 -> buf1
    WAITVM(4);
    barx();
    attn_tile<0>(qf, ones, kf_ptr, vf_ptr, pf_ptr, pw_ptr, sacc, oacc);
    barx();
    WAITVM(0);
    barx();
    attn_tile<8192>(qf, ones, kf_ptr, vf_ptr, pf_ptr, pw_ptr, sacc, oacc);
#undef AISSUE

    int b = bh / NHEAD, hh = bh - b * NHEAD;
#pragma unroll
    for (int h = 0; h < 2; h++){
        float rd = 1.0f / sacc[h][0];
        size_t row = (size_t)(b * SEQ + q0 + h*16 + l15);
#pragma unroll
        for (int dn = 0; dn < 4; dn++){
            float v0 = oacc[h][dn][0] * rd, v1 = oacc[h][dn][1] * rd;
            float v2 = oacc[h][dn][2] * rd, v3 = oacc[h][dn][3] * rd;
            unsigned int w0 = (unsigned int)f2bf(v0) | ((unsigned int)f2bf(v1) << 16);
            unsigned int w1 = (unsigned int)f2bf(v2) | ((unsigned int)f2bf(v3) << 16);
            *(uint2*)(O + row * DIM + hh * 64 + dn * 16 + quad * 4) = make_uint2(w0, w1);
        }
    }
}

// ---------------- launcher ----------------
extern "C" void kernel_launch(void* const* d_in, const int* in_sizes, int n_in,
                              void* d_out, int out_size, void* d_ws, size_t ws_size,
                              hipStream_t stream){
    const float* x      = (const float*)d_in[0];
    const float* ln1_g  = (const float*)d_in[1];
    const float* ln1_b  = (const float*)d_in[2];
    const float* qkv_w  = (const float*)d_in[3];
    const float* qkv_b  = (const float*)d_in[4];
    const float* proj_w = (const float*)d_in[5];
    const float* proj_b = (const float*)d_in[6];
    const float* ln2_g  = (const float*)d_in[7];
    const float* ln2_b  = (const float*)d_in[8];
    const float* fc1_w  = (const float*)d_in[9];
    const float* fc1_b  = (const float*)d_in[10];
    const float* fc2_w  = (const float*)d_in[11];
    const float* fc2_b  = (const float*)d_in[12];
    float* out = (float*)d_out;

    char* p = (char*)d_ws;
    auto take = [&](size_t n){ char* r = p; p += (n + 255) & ~(size_t)255; return r; };
    unsigned short* wt_qkv = (unsigned short*)take((size_t)1152 * 384 * 2);
    unsigned short* wt_prj = (unsigned short*)take((size_t)384 * 384 * 2);
    unsigned short* wt_fc1 = (unsigned short*)take((size_t)1536 * 384 * 2);
    unsigned short* wt_fc2 = (unsigned short*)take((size_t)384 * 1536 * 2);
    unsigned short* rbig   = (unsigned short*)take((size_t)MTOT * 4 * DIM * 2); // h1|q|k|v, later hm
    unsigned short* h2     = (unsigned short*)take((size_t)MTOT * DIM * 2);     // ln2 out
    float*          x1     = (float*)take((size_t)MTOT * DIM * 4);

    unsigned short* h1     = rbig;
    unsigned short* qb     = rbig + (size_t)MTOT * DIM;
    unsigned short* kb     = qb   + (size_t)MTOT * DIM;
    unsigned short* vb     = kb   + (size_t)MTOT * DIM;   // [bh][64][SEQ], written by qkv gemm
    unsigned short* attn_o = rbig;   // reuses h1 (dead after QKV gemm)
    unsigned short* hm     = rbig;   // reuses h1+qkv (dead after proj)

    wt_ln_kernel<<<dim3(432 + MTOT/4), 256, 0, stream>>>(qkv_w, proj_w, fc1_w, fc2_w,
                                                         wt_qkv, wt_prj, wt_fc1, wt_fc2,
                                                         x, ln1_g, ln1_b, h1);
    gemm_kernel<0,9,384><<<dim3(2304), 256, 0, stream>>>(h1, wt_qkv, qkv_b, 1152,
                                                     nullptr, nullptr, nullptr, qb, kb, vb);
    attn_kernel<<<dim3(768), 256, 0, stream>>>(qb, kb, vb, attn_o);
    gemm_kernel<1,3,384><<<dim3(768), 256, 0, stream>>>(attn_o, wt_prj, proj_b, 384,
                                                    x, x1, nullptr, nullptr, nullptr, nullptr);
    ln_kernel<<<dim3(MTOT/4), 256, 0, stream>>>(x1, ln2_g, ln2_b, h2);
    gemm_kernel<2,12,384><<<dim3(3072), 256, 0, stream>>>(h2, wt_fc1, fc1_b, 1536,
                                                      nullptr, nullptr, hm, nullptr, nullptr, nullptr);
    gemm_kernel<1,3,1536><<<dim3(768), 256, 0, stream>>>(hm, wt_fc2, fc2_b, 384,
                                                    x1, out, nullptr, nullptr, nullptr, nullptr);
}